// Round 1
// baseline (245.076 us; speedup 1.0000x reference)
//
#include <hip/hip_runtime.h>
#include <stdint.h>
#include <math.h>

// ---------------- LDS layout (static, < 64KB) ----------------
#define SMEM_H     0        // 32768 B: h (later xs2) as bf16 pairs: u32[128*64]
#define SMEM_SRC   32768    // 4096 B: att_src [8][128]
#define SMEM_DST   36864    // 4096 B: att_dst [8][128]
#define SMEM_MASK  40960    // 2048 B: mask bits [128 rows][4 u32]
#define SMEM_RED   43008    // 256 B : reduction scratch
#define SMEM_AS    43264    // 8448 B: As[16][132]; reused as mx[8*128], zi[8*128]
#define SMEM_BS    51712    // 8192 B: Bs[16][128]; reused as w2_l[256], dst2_l[128]
#define SMEM_SIZE  59904

#define WS_MASK_BYTES 262144   // 128*128 rows * 16 B

__device__ __forceinline__ float bf_lo(uint32_t u){ union {uint32_t i; float f;} v; v.i = u<<16; return v.f; }
__device__ __forceinline__ float bf_hi(uint32_t u){ union {uint32_t i; float f;} v; v.i = u & 0xffff0000u; return v.f; }
__device__ __forceinline__ uint32_t packbf(float a, float b){
  uint32_t ua = __float_as_uint(a), ub = __float_as_uint(b);
  uint32_t ra = (ua + 0x7fffu + ((ua>>16)&1u)) >> 16;   // RNE bf16
  uint32_t rb = (ub + 0x7fffu + ((ub>>16)&1u)) >> 16;
  return ra | (rb<<16);
}

// ---- pack adjacency (b,n,n) int32 -> per-row 128-bit masks ----
__global__ void mask_build(const int* __restrict__ adj, uint32_t* __restrict__ mask_ws) {
  const int t = threadIdx.x;
  const int row = blockIdx.x*4 + (t>>6);   // 4 waves/block, one row per wave
  const int lane = t & 63;
  const int* ar = adj + (size_t)row*128;
  uint64_t m0 = __ballot(ar[lane] != 0);
  uint64_t m1 = __ballot(ar[64+lane] != 0);
  if (lane == 0) {
    ((uint4*)mask_ws)[row] = make_uint4((uint32_t)m0, (uint32_t)(m0>>32),
                                        (uint32_t)m1, (uint32_t)(m1>>32));
  }
}

// ---- fused GAT: one block per (s, b) ----
__global__ __launch_bounds__(256,2) void gat_fused(
    const float* __restrict__ x,  const float* __restrict__ emb,
    const float* __restrict__ w1, const float* __restrict__ a_src1,
    const float* __restrict__ a_dst1, const float* __restrict__ b1,
    const float* __restrict__ w2, const float* __restrict__ a_src2,
    const float* __restrict__ a_dst2, const float* __restrict__ b2,
    const uint32_t* __restrict__ mask_ws, float* __restrict__ logp_ws)
{
  __shared__ __align__(16) char smem[SMEM_SIZE];
  uint32_t* h_u    = (uint32_t*)(smem + SMEM_H);
  float*    src_l  = (float*)(smem + SMEM_SRC);
  float*    dst_l  = (float*)(smem + SMEM_DST);
  uint32_t* mask_l = (uint32_t*)(smem + SMEM_MASK);
  float*    red    = (float*)(smem + SMEM_RED);
  float*    As     = (float*)(smem + SMEM_AS);
  float*    Bs     = (float*)(smem + SMEM_BS);
  float*    mx_l   = (float*)(smem + SMEM_AS);          // after GEMM done
  float*    zi_l   = (float*)(smem + SMEM_AS + 4096);
  float*    w2_l   = (float*)(smem + SMEM_BS);          // after GEMM done
  float*    d2_l   = (float*)(smem + SMEM_BS + 1024);

  const int t  = threadIdx.x;
  const int s  = blockIdx.x >> 7;
  const int bb = blockIdx.x & 127;

  // stage this batch-element's mask rows (128 rows x 4 u32)
  {
    const uint32_t* mrow = mask_ws + (size_t)bb*512;
    mask_l[t]     = mrow[t];
    mask_l[256+t] = mrow[256+t];
  }

  // ---------- Phase 1: h[i][col] = sum_f x0[i][f]*W1[f][col], col = head*16+of ----------
  const float* w1s = w1 + (size_t)s*16384;              // (8,128,16)
  const int ty = t >> 4, tx = t & 15;                   // 16x16 threads, 8x8 tile each
  const int ia = t >> 1, k0 = (t&1)*8;                  // A-tile load mapping
  float acc[8][8];
  #pragma unroll
  for (int ii=0; ii<8; ++ii)
    #pragma unroll
    for (int oo=0; oo<8; ++oo) acc[ii][oo] = 0.f;

  for (int kb=0; kb<8; ++kb) {                          // K chunks of 16 (k<64: x, else emb)
    const float* srcA = (kb<4 ? x : emb) + (size_t)bb*8192 + ia*64 + (kb&3)*16 + k0;
    float4 a0 = *(const float4*)srcA;
    float4 a1 = *(const float4*)(srcA+4);
    const int kkb = t>>4, o0 = (t*8)&127;
    const float* srcB = w1s + (o0>>4)*2048 + (kb*16+kkb)*16 + (o0&15);
    float4 bv0 = *(const float4*)srcB;
    float4 bv1 = *(const float4*)(srcB+4);
    __syncthreads();
    As[(k0+0)*132+ia]=a0.x; As[(k0+1)*132+ia]=a0.y; As[(k0+2)*132+ia]=a0.z; As[(k0+3)*132+ia]=a0.w;
    As[(k0+4)*132+ia]=a1.x; As[(k0+5)*132+ia]=a1.y; As[(k0+6)*132+ia]=a1.z; As[(k0+7)*132+ia]=a1.w;
    *(float4*)&Bs[kkb*128+o0]   = bv0;
    *(float4*)&Bs[kkb*128+o0+4] = bv1;
    __syncthreads();
    #pragma unroll
    for (int kk=0; kk<16; ++kk) {
      float4 af0 = *(const float4*)&As[kk*132+ty*8];
      float4 af1 = *(const float4*)&As[kk*132+ty*8+4];
      float4 bf0 = *(const float4*)&Bs[kk*128+tx*8];
      float4 bf1 = *(const float4*)&Bs[kk*128+tx*8+4];
      float av[8] = {af0.x,af0.y,af0.z,af0.w,af1.x,af1.y,af1.z,af1.w};
      float bw[8] = {bf0.x,bf0.y,bf0.z,bf0.w,bf1.x,bf1.y,bf1.z,bf1.w};
      #pragma unroll
      for (int ii=0; ii<8; ++ii)
        #pragma unroll
        for (int oo=0; oo<8; ++oo)
          acc[ii][oo] = fmaf(av[ii], bw[oo], acc[ii][oo]);
    }
  }

  // epilogue: tanh -> att_src/att_dst partials (pair shfl-reduce); store h as bf16
  {
    const int head = tx>>1;
    const float* asv = a_src1 + s*128 + head*16 + (tx&1)*8;
    const float* adv = a_dst1 + s*128 + head*16 + (tx&1)*8;
    float av[8], dv[8];
    #pragma unroll
    for (int k=0;k<8;++k){ av[k]=asv[k]; dv[k]=adv[k]; }
    #pragma unroll
    for (int ii=0; ii<8; ++ii) {
      float ps=0.f, pd=0.f;
      #pragma unroll
      for (int oo=0; oo<8; ++oo) {
        float th = tanhf(acc[ii][oo]);
        ps = fmaf(th, av[oo], ps);
        pd = fmaf(th, dv[oo], pd);
      }
      ps += __shfl_xor(ps,1);
      pd += __shfl_xor(pd,1);
      if ((tx&1)==0) {
        src_l[head*128 + ty*8+ii] = ps;
        dst_l[head*128 + ty*8+ii] = pd;
      }
      uint4 hu = make_uint4(packbf(acc[ii][0],acc[ii][1]), packbf(acc[ii][2],acc[ii][3]),
                            packbf(acc[ii][4],acc[ii][5]), packbf(acc[ii][6],acc[ii][7]));
      ((uint4*)h_u)[(ty*8+ii)*16 + tx] = hu;
    }
  }
  __syncthreads();

  // ---------- Phase 2a: per (head,row) softmax stats: max and 1/Z ----------
  for (int rep=0; rep<4; ++rep) {
    const int rid = rep*256 + t;           // rid = head*128 + r
    const int r = rid & 127;
    const float sr = src_l[rid];
    const float* dl = dst_l + (rid>>7)*128;
    uint32_t mw0=mask_l[r*4+0], mw1=mask_l[r*4+1], mw2=mask_l[r*4+2], mw3=mask_l[r*4+3];
    float m = -3.0e38f;
    #pragma unroll
    for (int w=0; w<4; ++w) {
      uint32_t mm = (w==0)?mw0:(w==1)?mw1:(w==2)?mw2:mw3;
      #pragma unroll 8
      for (int jj=0; jj<32; ++jj) {
        float t0 = sr + dl[w*32+jj];
        float lr = fmaxf(t0, 0.2f*t0);
        float v  = ((mm>>jj)&1u) ? lr : -1e9f;
        m = fmaxf(m, v);
      }
    }
    float z = 0.f;
    #pragma unroll
    for (int w=0; w<4; ++w) {
      uint32_t mm = (w==0)?mw0:(w==1)?mw1:(w==2)?mw2:mw3;
      #pragma unroll 8
      for (int jj=0; jj<32; ++jj) {
        float t0 = sr + dl[w*32+jj];
        float lr = fmaxf(t0, 0.2f*t0);
        float v  = ((mm>>jj)&1u) ? lr : -1e9f;
        z += __expf(v - m);
      }
    }
    mx_l[rid] = m;
    zi_l[rid] = 1.f/z;
  }
  __syncthreads();

  // ---------- Phase 2b: out1 = softmax(logits) @ h, + b1, elu; write xs2 ----------
  float outv[8][8];
  {
    const int hd = t >> 5, rg = (t>>1)&15, og = t&1;    // 8 heads x 16 rowgrp x 2 colgrp
    float sr8[8], m8[8], z8[8], b1v[8];
    #pragma unroll
    for (int ii=0; ii<8; ++ii) {
      const int r = rg*8+ii;
      sr8[ii] = src_l[hd*128+r];
      m8[ii]  = mx_l[hd*128+r];
      z8[ii]  = zi_l[hd*128+r];
      b1v[ii] = b1[og*8+ii];        // indexed by column k later (same 8 values)
    }
    float acc2[8][8];
    #pragma unroll
    for (int ii=0; ii<8; ++ii)
      #pragma unroll
      for (int k=0;k<8;++k) acc2[ii][k]=0.f;
    const float* dl2 = dst_l + hd*128;
    const uint4* hp = (const uint4*)h_u;
    #pragma unroll
    for (int w=0; w<4; ++w) {
      uint32_t mcur[8];
      #pragma unroll
      for (int ii=0; ii<8; ++ii) mcur[ii] = mask_l[(rg*8+ii)*4 + w];
      #pragma unroll 2
      for (int jj=0; jj<32; ++jj) {
        const int j = w*32+jj;
        const float dj = dl2[j];
        uint4 hu = hp[j*16 + hd*2 + og];
        float hf[8] = { bf_lo(hu.x), bf_hi(hu.x), bf_lo(hu.y), bf_hi(hu.y),
                        bf_lo(hu.z), bf_hi(hu.z), bf_lo(hu.w), bf_hi(hu.w) };
        #pragma unroll
        for (int ii=0; ii<8; ++ii) {
          float t0 = sr8[ii] + dj;
          float lr = fmaxf(t0, 0.2f*t0);
          float e  = __expf(lr - m8[ii]);
          e = ((mcur[ii]>>jj)&1u) ? e : 0.f;
          #pragma unroll
          for (int k=0;k<8;++k) acc2[ii][k] = fmaf(e, hf[k], acc2[ii][k]);
        }
      }
    }
    #pragma unroll
    for (int ii=0; ii<8; ++ii)
      #pragma unroll
      for (int k=0;k<8;++k) {
        float o = fmaf(acc2[ii][k], z8[ii], b1v[k]);
        outv[ii][k] = (o > 0.f) ? o : expm1f(o);        // elu
      }
    __syncthreads();   // all h reads complete before overwriting region with xs2
    uint4* hw = (uint4*)h_u;
    #pragma unroll
    for (int ii=0; ii<8; ++ii) {
      uint4 u = make_uint4(packbf(outv[ii][0],outv[ii][1]), packbf(outv[ii][2],outv[ii][3]),
                           packbf(outv[ii][4],outv[ii][5]), packbf(outv[ii][6],outv[ii][7]));
      hw[(rg*8+ii)*16 + hd*2 + og] = u;
    }
  }
  w2_l[t] = w2[s*256 + t];                               // stage W2 (128x2)
  __syncthreads();

  // ---------- Layer 2 (ego row only) + log_softmax ----------
  {
    const int jn = t>>1, c = t&1;                        // node jn, class c
    float hv = 0.f;
    const uint32_t* xr = h_u + jn*64;
    #pragma unroll 8
    for (int f2=0; f2<64; ++f2) {
      uint32_t u = xr[f2];
      hv = fmaf(bf_lo(u), w2_l[f2*4 + c], hv);
      hv = fmaf(bf_hi(u), w2_l[f2*4 + 2 + c], hv);
    }
    float th2 = tanhf(hv);
    float ps = th2 * a_src2[s*2+c];
    float pd = th2 * a_dst2[s*2+c];
    ps += __shfl_xor(ps,1);
    pd += __shfl_xor(pd,1);
    if (c==0) d2_l[jn] = pd;
    if (t==254) red[48] = ps;                            // ego node (jn=127) src term
    __syncthreads();

    const float src_e = red[48];
    float t0 = src_e + d2_l[jn];
    float lg = fmaxf(t0, 0.2f*t0);
    uint32_t bit = (mask_l[127*4 + (jn>>5)] >> (jn&31)) & 1u;
    float v = bit ? lg : -1e9f;

    float mloc = v;
    #pragma unroll
    for (int off=32; off>=1; off>>=1) mloc = fmaxf(mloc, __shfl_xor(mloc, off));
    if ((t&63)==0) red[t>>6] = mloc;
    __syncthreads();
    const float M = fmaxf(fmaxf(red[0],red[1]), fmaxf(red[2],red[3]));

    float e  = __expf(v - M);
    float vA = e * hv;                                   // per-class weighted sum
    float vZ = (c==0) ? e : 0.f;                         // partition counted once
    #pragma unroll
    for (int off=2; off<=32; off<<=1) { vA += __shfl_xor(vA, off); vZ += __shfl_xor(vZ, off); }
    if ((t&63)==0) { red[8 + (t>>6)*2 + 0] = vA; red[16 + (t>>6)] = vZ; }
    if ((t&63)==1) { red[8 + (t>>6)*2 + 1] = vA; }
    __syncthreads();
    if (t==0) {
      float S0 = red[8]+red[10]+red[12]+red[14];
      float S1 = red[9]+red[11]+red[13]+red[15];
      float Z  = red[16]+red[17]+red[18]+red[19];
      float o0 = S0/Z + b2[0];
      float o1 = S1/Z + b2[1];
      float mm = fmaxf(o0,o1);
      float lse = mm + logf(__expf(o0-mm)+__expf(o1-mm));
      logp_ws[(s*128+bb)*2+0] = o0 - lse;
      logp_ws[(s*128+bb)*2+1] = o1 - lse;
    }
  }
}

// ---- mean over S samples ----
__global__ void reduce_s(const float* __restrict__ lp, float* __restrict__ out) {
  const int t = threadIdx.x;  // 256 = b*2
  out[t] = 0.25f*(lp[t] + lp[256+t] + lp[512+t] + lp[768+t]);
}

extern "C" void kernel_launch(void* const* d_in, const int* in_sizes, int n_in,
                              void* d_out, int out_size, void* d_ws, size_t ws_size,
                              hipStream_t stream) {
  const float* x      = (const float*)d_in[0];
  const float* emb    = (const float*)d_in[1];
  const int*   adj    = (const int*)d_in[2];
  const float* w1     = (const float*)d_in[3];
  const float* a_src1 = (const float*)d_in[4];
  const float* a_dst1 = (const float*)d_in[5];
  const float* b1     = (const float*)d_in[6];
  const float* w2     = (const float*)d_in[7];
  const float* a_src2 = (const float*)d_in[8];
  const float* a_dst2 = (const float*)d_in[9];
  const float* b2     = (const float*)d_in[10];

  uint32_t* mask_ws = (uint32_t*)d_ws;
  float*    logp_ws = (float*)((char*)d_ws + WS_MASK_BYTES);

  mask_build<<<dim3(4096), dim3(256), 0, stream>>>(adj, mask_ws);
  gat_fused<<<dim3(512), dim3(256), 0, stream>>>(x, emb, w1, a_src1, a_dst1, b1,
                                                 w2, a_src2, a_dst2, b2,
                                                 mask_ws, logp_ws);
  reduce_s<<<dim3(1), dim3(256), 0, stream>>>(logp_ws, (float*)d_out);
}

// Round 2
// 140.923 us; speedup vs baseline: 1.7391x; 1.7391x over previous
//
#include <hip/hip_runtime.h>
#include <stdint.h>
#include <math.h>

typedef __attribute__((ext_vector_type(8))) short short8;
typedef __attribute__((ext_vector_type(4))) float floatx4;

// ---------------- LDS layout (static, 60160 B) ----------------
#define L_HU    0        // 32768: h bf16 row-major, u32[128][64] (pairs of cols)
#define L_BF    32768    // 16384: W1 B-frags (phase1); h2 partials in phase2 (8*128*8=8192)
#define L_SRC   49152    // 4096: att_src [8][128] f32
#define L_DST   53248    // 4096: att_dst [8][128] f32
#define L_MASK  57344    // 2048: mask bits [128 rows][16 B]
#define L_RED   59392    // 256 : reduction scratch (64 floats)
#define L_D2    59648    // 512 : layer2 dst term [128]
#define L_SIZE  60160

#define WS_MASK_BYTES 262144   // 128*128 rows * 16 B

union F8 { short8 s8; uint32_t u[4]; };

__device__ __forceinline__ uint32_t packbf(float a, float b){
  uint32_t ua = __float_as_uint(a), ub = __float_as_uint(b);
  uint32_t ra = (ua + 0x7fffu + ((ua>>16)&1u)) >> 16;   // RNE bf16
  uint32_t rb = (ub + 0x7fffu + ((ub>>16)&1u)) >> 16;
  return ra | (rb<<16);
}
__device__ __forceinline__ float fast_tanh(float x){
  // 1 - 2/(e^{2x}+1); rcp rel err ~1e-6, saturates correctly at +-inf
  float e = __expf(2.f*x);
  return 1.f - 2.f*__builtin_amdgcn_rcpf(e + 1.f);
}

// ---- pack adjacency (b,n,n) int32 -> per-row 128-bit masks ----
__global__ void mask_build(const int* __restrict__ adj, uint32_t* __restrict__ mask_ws) {
  const int t = threadIdx.x;
  const int row = blockIdx.x*4 + (t>>6);   // 4 waves/block, one row per wave
  const int lane = t & 63;
  const int* ar = adj + (size_t)row*128;
  uint64_t m0 = __ballot(ar[lane] != 0);
  uint64_t m1 = __ballot(ar[64+lane] != 0);
  if (lane == 0) {
    ((uint4*)mask_ws)[row] = make_uint4((uint32_t)m0, (uint32_t)(m0>>32),
                                        (uint32_t)m1, (uint32_t)(m1>>32));
  }
}

// ---- fused GAT: one block per (s, b), 8 waves ----
__global__ __launch_bounds__(512,4) void gat_fused(
    const float* __restrict__ x,  const float* __restrict__ emb,
    const float* __restrict__ w1, const float* __restrict__ a_src1,
    const float* __restrict__ a_dst1, const float* __restrict__ b1,
    const float* __restrict__ w2, const float* __restrict__ a_src2,
    const float* __restrict__ a_dst2, const float* __restrict__ b2,
    const uint32_t* __restrict__ mask_ws, float* __restrict__ logp_ws)
{
  __shared__ __align__(16) char smem[L_SIZE];
  uint32_t* h_u   = (uint32_t*)(smem + L_HU);
  uint16_t* h_u16 = (uint16_t*)(smem + L_HU);
  char*     bf_b  = smem + L_BF;
  float2*   h2p   = (float2*)(smem + L_BF);
  float*    src_l = (float*)(smem + L_SRC);
  float*    dst_l = (float*)(smem + L_DST);
  uint32_t* mask_l= (uint32_t*)(smem + L_MASK);
  const uint4* mask4 = (const uint4*)(smem + L_MASK);
  float*    red   = (float*)(smem + L_RED);
  float*    d2_l  = (float*)(smem + L_D2);

  const int t  = threadIdx.x;
  const int s  = blockIdx.x >> 7;
  const int bb = blockIdx.x & 127;
  const int lane = t & 63, w = t >> 6;
  const int of = lane & 15, kg = lane >> 4;

  // stage mask (512 u32)
  mask_l[t] = mask_ws[(size_t)bb*512 + t];

  // ---------- Phase 1: h = x0 @ W1 via MFMA ----------
  // A-frags direct from global: wave w owns rows w*16..w*16+15
  const int arow = w*16 + of;
  const float* xrow = x   + ((size_t)bb*128 + arow)*64;
  const float* erow = emb + ((size_t)bb*128 + arow)*64;
  short8 af[4];
  #pragma unroll
  for (int ks=0; ks<4; ++ks){
    int k = ks*32 + kg*8;
    const float* p = (k<64) ? (xrow+k) : (erow + (k-64));
    float4 f0 = *(const float4*)p, f1 = *(const float4*)(p+4);
    F8 fr;
    fr.u[0]=packbf(f0.x,f0.y); fr.u[1]=packbf(f0.z,f0.w);
    fr.u[2]=packbf(f1.x,f1.y); fr.u[3]=packbf(f1.z,f1.w);
    af[ks]=fr.s8;
  }

  const float* w1s = w1 + (size_t)s*16384;       // (8,128,16)
  floatx4 acc[8];
  #pragma unroll
  for (int ct=0; ct<8; ++ct) acc[ct]=(floatx4){0.f,0.f,0.f,0.f};

  for (int c=0; c<2; ++c){                        // K chunks of 64
    if (c) __syncthreads();                       // prev chunk's B reads done
    #pragma unroll
    for (int r=0; r<2; ++r){                      // stage W1 frags (frag-order)
      int q  = t + r*512;                         // 0..1023 tuples
      int ln = q & 63, ks2 = (q>>6)&1, ct = q>>7;
      int kk = (c*2+ks2)*32 + (ln>>4)*8;
      int oo = ln & 15;
      const float* wp = w1s + ct*2048 + kk*16 + oo;
      float v0=wp[0],  v1=wp[16], v2=wp[32], v3=wp[48];
      float v4=wp[64], v5=wp[80], v6=wp[96], v7=wp[112];
      F8 fr;
      fr.u[0]=packbf(v0,v1); fr.u[1]=packbf(v2,v3);
      fr.u[2]=packbf(v4,v5); fr.u[3]=packbf(v6,v7);
      *(short8*)(bf_b + ((ct*2+ks2)*64 + ln)*16) = fr.s8;
    }
    __syncthreads();
    #pragma unroll
    for (int ct=0; ct<8; ++ct)
      #pragma unroll
      for (int ks2=0; ks2<2; ++ks2){
        short8 bfr = *(const short8*)(bf_b + ((ct*2+ks2)*64 + lane)*16);
        acc[ct] = __builtin_amdgcn_mfma_f32_16x16x32_bf16(af[c*2+ks2], bfr, acc[ct], 0,0,0);
      }
  }

  // epilogue: tanh->att partials (shfl reduce over of), h -> LDS bf16 row-major
  #pragma unroll
  for (int ct=0; ct<8; ++ct){
    float asv = a_src1[s*128 + ct*16 + of];
    float adv = a_dst1[s*128 + ct*16 + of];
    float ps[4], pd[4];
    #pragma unroll
    for (int r=0; r<4; ++r){
      float th = fast_tanh(acc[ct][r]);
      ps[r] = th*asv; pd[r] = th*adv;
    }
    #pragma unroll
    for (int off=1; off<16; off<<=1)
      #pragma unroll
      for (int r=0; r<4; ++r){ ps[r]+=__shfl_xor(ps[r],off); pd[r]+=__shfl_xor(pd[r],off); }
    if (of==0){
      #pragma unroll
      for (int r=0; r<4; ++r){
        int i = w*16 + kg*4 + r;
        src_l[ct*128+i]=ps[r]; dst_l[ct*128+i]=pd[r];
      }
    }
    #pragma unroll
    for (int r=0; r<4; ++r){
      float pv = __shfl_xor(acc[ct][r],1);
      if ((of&1)==0){
        int i = w*16 + kg*4 + r;
        h_u[i*64 + ct*8 + (of>>1)] = packbf(acc[ct][r], pv);
      }
    }
  }
  __syncthreads();

  // ---------- Phase 2: out1 = softmax(lrelu(src+dst)) @ h, fused elu + W2 dot ----------
  const int hd = w;                               // one head per wave
  float b1v  = b1[of];
  float w2c0 = w2[s*256 + (hd*16+of)*2 + 0];
  float w2c1 = w2[s*256 + (hd*16+of)*2 + 1];
  short8 hb[4];                                   // B-frags: h[j][hd*16+of]
  #pragma unroll
  for (int ks=0; ks<4; ++ks){
    F8 fr;
    #pragma unroll
    for (int v=0; v<4; ++v){
      int j = ks*32 + kg*8 + 2*v;
      uint32_t lo = h_u16[j*128     + hd*16 + of];
      uint32_t hi = h_u16[(j+1)*128 + hd*16 + of];
      fr.u[v] = lo | (hi<<16);
    }
    hb[ks]=fr.s8;
  }

  for (int rt=0; rt<8; ++rt){
    const int im = rt*16 + of;                    // A-layout row
    float srcv = src_l[hd*128 + im];
    uint4 mrow = mask4[im];
    floatx4 acc2 = (floatx4){0.f,0.f,0.f,0.f};
    float zp = 0.f;
    #pragma unroll
    for (int ks=0; ks<4; ++ks){
      const float* dp = dst_l + hd*128 + ks*32 + kg*8;
      float4 d0 = *(const float4*)dp, d1 = *(const float4*)(dp+4);
      uint32_t mw = (ks==0)?mrow.x:(ks==1)?mrow.y:(ks==2)?mrow.z:mrow.w;
      uint32_t mbyte = mw >> (kg*8);
      float dj[8] = {d0.x,d0.y,d0.z,d0.w,d1.x,d1.y,d1.z,d1.w};
      float e[8];
      #pragma unroll
      for (int jj=0; jj<8; ++jj){
        float t0 = srcv + dj[jj];
        float lr = fmaxf(t0, 0.2f*t0);
        float ev = __expf(lr);                    // no max-sub: logits bounded
        ev = ((mbyte>>jj)&1u) ? ev : 0.f;
        e[jj]=ev; zp += ev;
      }
      F8 fr;
      fr.u[0]=packbf(e[0],e[1]); fr.u[1]=packbf(e[2],e[3]);
      fr.u[2]=packbf(e[4],e[5]); fr.u[3]=packbf(e[6],e[7]);
      acc2 = __builtin_amdgcn_mfma_f32_16x16x32_bf16(fr.s8, hb[ks], acc2, 0,0,0);
    }
    float zr = zp + __shfl_xor(zp,16); zr += __shfl_xor(zr,32);
    float zi = __builtin_amdgcn_rcpf(zr);
    float pc0[4], pc1[4];
    #pragma unroll
    for (int r=0; r<4; ++r){
      float ziR = __shfl(zi, kg*4+r);             // zi for C row kg*4+r
      float o  = fmaf(acc2[r], ziR, b1v);
      float oe = (o>0.f) ? o : (__expf(o)-1.f);   // elu
      pc0[r]=oe*w2c0; pc1[r]=oe*w2c1;
    }
    #pragma unroll
    for (int off=1; off<16; off<<=1)
      #pragma unroll
      for (int r=0; r<4; ++r){ pc0[r]+=__shfl_xor(pc0[r],off); pc1[r]+=__shfl_xor(pc1[r],off); }
    if (of==0){
      #pragma unroll
      for (int r=0; r<4; ++r){
        int i = rt*16 + kg*4 + r;
        h2p[w*128 + i] = make_float2(pc0[r], pc1[r]);  // per-wave partial (overlays bf_b)
      }
    }
  }
  __syncthreads();

  // ---------- Layer 2 (ego row only) + log_softmax ----------
  {
    const int jn = t>>1, cc = t&1;
    const bool act = (t<256);
    float hv=0.f, v=-1e9f;
    if (act){
      #pragma unroll
      for (int ww=0; ww<8; ++ww){
        float2 p = h2p[ww*128+jn];
        hv += cc ? p.y : p.x;
      }
      float th2 = fast_tanh(hv);
      float ps2 = th2*a_src2[s*2+cc];
      float pd2 = th2*a_dst2[s*2+cc];
      ps2 += __shfl_xor(ps2,1);
      pd2 += __shfl_xor(pd2,1);
      if (cc==0) d2_l[jn]=pd2;
      if (t==254) red[40]=ps2;                    // ego node (jn=127)
    }
    __syncthreads();
    if (act){
      float t0 = red[40] + d2_l[jn];
      float lg = fmaxf(t0, 0.2f*t0);
      uint32_t bit = (mask_l[127*4 + (jn>>5)] >> (jn&31)) & 1u;
      v = bit ? lg : -1e9f;
    }
    float mloc = v;
    #pragma unroll
    for (int off=32; off>=1; off>>=1) mloc = fmaxf(mloc, __shfl_xor(mloc,off));
    if (lane==0) red[w]=mloc;
    __syncthreads();
    float M = fmaxf(fmaxf(red[0],red[1]), fmaxf(red[2],red[3]));
    float e2 = act ? __expf(v-M) : 0.f;
    float vA = e2*hv;
    float vZ = (cc==0 && act) ? e2 : 0.f;
    #pragma unroll
    for (int off=2; off<=32; off<<=1){ vA+=__shfl_xor(vA,off); vZ+=__shfl_xor(vZ,off); }
    if (lane==0){ red[8+w]=vA; red[24+w]=vZ; }
    if (lane==1){ red[16+w]=vA; }
    __syncthreads();
    if (t==0){
      float S0 = red[8]+red[9]+red[10]+red[11];
      float S1 = red[16]+red[17]+red[18]+red[19];
      float Z  = red[24]+red[25]+red[26]+red[27];
      float o0 = S0/Z + b2[0];
      float o1 = S1/Z + b2[1];
      float mm = fmaxf(o0,o1);
      float lse = mm + logf(__expf(o0-mm)+__expf(o1-mm));
      logp_ws[(s*128+bb)*2+0] = o0 - lse;
      logp_ws[(s*128+bb)*2+1] = o1 - lse;
    }
  }
}

// ---- mean over S samples ----
__global__ void reduce_s(const float* __restrict__ lp, float* __restrict__ out) {
  const int t = threadIdx.x;  // 256 = b*2
  out[t] = 0.25f*(lp[t] + lp[256+t] + lp[512+t] + lp[768+t]);
}

extern "C" void kernel_launch(void* const* d_in, const int* in_sizes, int n_in,
                              void* d_out, int out_size, void* d_ws, size_t ws_size,
                              hipStream_t stream) {
  const float* x      = (const float*)d_in[0];
  const float* emb    = (const float*)d_in[1];
  const int*   adj    = (const int*)d_in[2];
  const float* w1     = (const float*)d_in[3];
  const float* a_src1 = (const float*)d_in[4];
  const float* a_dst1 = (const float*)d_in[5];
  const float* b1     = (const float*)d_in[6];
  const float* w2     = (const float*)d_in[7];
  const float* a_src2 = (const float*)d_in[8];
  const float* a_dst2 = (const float*)d_in[9];
  const float* b2     = (const float*)d_in[10];

  uint32_t* mask_ws = (uint32_t*)d_ws;
  float*    logp_ws = (float*)((char*)d_ws + WS_MASK_BYTES);

  mask_build<<<dim3(4096), dim3(256), 0, stream>>>(adj, mask_ws);
  gat_fused<<<dim3(512), dim3(512), 0, stream>>>(x, emb, w1, a_src1, a_dst1, b1,
                                                 w2, a_src2, a_dst2, b2,
                                                 mask_ws, logp_ws);
  reduce_s<<<dim3(1), dim3(256), 0, stream>>>(logp_ws, (float*)d_out);
}

// Round 3
// 139.829 us; speedup vs baseline: 1.7527x; 1.0078x over previous
//
#include <hip/hip_runtime.h>
#include <stdint.h>
#include <math.h>

typedef __attribute__((ext_vector_type(8))) short short8;
typedef __attribute__((ext_vector_type(4))) float floatx4;

// ---------------- LDS layout (static, 51968 B -> 3 blocks/CU possible) ----------------
#define L_HF    0        // 32768: h in MFMA B-frag order: [ct(8)][ks(4)][lane(64)] x 16B
#define L_H2P   32768    // 8192 : layer-2 partials float2[8 waves][128 nodes]
#define L_SRC   40960    // 4096 : att_src [8][128] f32
#define L_DST   45056    // 4096 : att_dst [8][128] f32
#define L_MASK  49152    // 2048 : mask bits [128 rows][16 B]
#define L_RED   51200    // 256  : reduction scratch (64 floats)
#define L_D2    51456    // 512  : layer2 dst term [128]
#define L_SIZE  51968

#define WS_MASK_BYTES 262144   // 128*128 rows * 16 B
#define WS_W1F_BYTES  131072   // 4 s * 8 ct * 4 ks * 64 lanes * 16 B

union F8 { short8 s8; uint32_t u[4]; };

__device__ __forceinline__ uint32_t packbf(float a, float b){
  uint32_t ua = __float_as_uint(a), ub = __float_as_uint(b);
  uint32_t ra = (ua + 0x7fffu + ((ua>>16)&1u)) >> 16;   // RNE bf16
  uint32_t rb = (ub + 0x7fffu + ((ub>>16)&1u)) >> 16;
  return ra | (rb<<16);
}
__device__ __forceinline__ float fast_tanh(float x){
  float e = __expf(2.f*x);
  return 1.f - 2.f*__builtin_amdgcn_rcpf(e + 1.f);
}

// ---- prep: adjacency -> bitmasks (blocks 0..1023), W1 -> bf16 B-frags (blocks 1024..1055) ----
__global__ void prep(const int* __restrict__ adj, const float* __restrict__ w1,
                     uint32_t* __restrict__ mask_ws, uint32_t* __restrict__ w1f) {
  const int blk = blockIdx.x, t = threadIdx.x;
  if (blk < 1024) {                       // 16 rows/block, 4 rows/wave
    const int lane = t & 63;
    const int row0 = blk*16 + (t>>6)*4;
    #pragma unroll
    for (int i=0;i<4;++i){
      const int row = row0 + i;
      const int* ar = adj + (size_t)row*128;
      uint64_t m0 = __ballot(ar[lane] != 0);
      uint64_t m1 = __ballot(ar[64+lane] != 0);
      if (lane == 0)
        ((uint4*)mask_ws)[row] = make_uint4((uint32_t)m0,(uint32_t)(m0>>32),
                                            (uint32_t)m1,(uint32_t)(m1>>32));
    }
  } else {                                // w1 (S,8,128,16) fp32 -> frag-order bf16
    const int tid = (blk-1024)*256 + t;   // 0..8191 = ((s*8+ct)*4+ks)*64+lane
    const int lane = tid & 63, ks = (tid>>6)&3, ct = (tid>>8)&7, s = tid>>11;
    const float* wp = w1 + s*16384 + ct*2048 + (ks*32 + (lane>>4)*8)*16 + (lane&15);
    uint4 u;
    u.x = packbf(wp[0*16],  wp[1*16]);
    u.y = packbf(wp[2*16],  wp[3*16]);
    u.z = packbf(wp[4*16],  wp[5*16]);
    u.w = packbf(wp[6*16],  wp[7*16]);
    ((uint4*)w1f)[tid] = u;
  }
}

// ---- fused GAT: one block per (s, b), 8 waves ----
__global__ __launch_bounds__(512,4) void gat_fused(
    const float* __restrict__ x,  const float* __restrict__ emb,
    const float* __restrict__ a_src1, const float* __restrict__ a_dst1,
    const float* __restrict__ b1,
    const float* __restrict__ w2, const float* __restrict__ a_src2,
    const float* __restrict__ a_dst2, const float* __restrict__ b2,
    const uint32_t* __restrict__ mask_ws, const char* __restrict__ w1f,
    float* __restrict__ outp)
{
  __shared__ __align__(16) char smem[L_SIZE];
  char*     hf    = smem + L_HF;
  uint32_t* hf_u  = (uint32_t*)(smem + L_HF);
  float2*   h2p   = (float2*)(smem + L_H2P);
  float*    src_l = (float*)(smem + L_SRC);
  float*    dst_l = (float*)(smem + L_DST);
  uint32_t* mask_l= (uint32_t*)(smem + L_MASK);
  const uint4* mask4 = (const uint4*)(smem + L_MASK);
  float*    red   = (float*)(smem + L_RED);
  float*    d2_l  = (float*)(smem + L_D2);

  const int t  = threadIdx.x;
  const int s  = blockIdx.x >> 7;
  const int bb = blockIdx.x & 127;
  const int lane = t & 63, w = t >> 6;
  const int of = lane & 15, kg = lane >> 4;

  mask_l[t] = mask_ws[(size_t)bb*512 + t];

  // ---------- Phase 1: h = x0 @ W1 via MFMA (B-frags direct from prepacked global) ----------
  const int arow = w*16 + of;
  const float* xrow = x   + ((size_t)bb*128 + arow)*64;
  const float* erow = emb + ((size_t)bb*128 + arow)*64;
  short8 af[4];
  #pragma unroll
  for (int ks=0; ks<4; ++ks){
    int k = ks*32 + kg*8;
    const float* p = (k<64) ? (xrow+k) : (erow + (k-64));
    float4 f0 = *(const float4*)p, f1 = *(const float4*)(p+4);
    F8 fr;
    fr.u[0]=packbf(f0.x,f0.y); fr.u[1]=packbf(f0.z,f0.w);
    fr.u[2]=packbf(f1.x,f1.y); fr.u[3]=packbf(f1.z,f1.w);
    af[ks]=fr.s8;
  }

  const char* w1fs = w1f + (size_t)s*32768;       // 8ct*4ks*64lane*16B
  floatx4 acc[8];
  #pragma unroll
  for (int ct=0; ct<8; ++ct) acc[ct]=(floatx4){0.f,0.f,0.f,0.f};
  #pragma unroll
  for (int ct=0; ct<8; ++ct)
    #pragma unroll
    for (int ks=0; ks<4; ++ks){
      short8 bfr = *(const short8*)(w1fs + ((ct*4+ks)*64 + lane)*16);
      acc[ct] = __builtin_amdgcn_mfma_f32_16x16x32_bf16(af[ks], bfr, acc[ct], 0,0,0);
    }

  // epilogue: tanh -> att partials; h -> LDS directly in B-frag order (one b64/ct)
  const int ks_h = w>>1, kgp = (w&1)*2 + (kg>>1), vv = (kg&1)*2;
  #pragma unroll
  for (int ct=0; ct<8; ++ct){
    float asv = a_src1[s*128 + ct*16 + of];
    float adv = a_dst1[s*128 + ct*16 + of];
    float ps[4], pd[4];
    #pragma unroll
    for (int r=0; r<4; ++r){
      float th = fast_tanh(acc[ct][r]);
      ps[r] = th*asv; pd[r] = th*adv;
    }
    #pragma unroll
    for (int off=1; off<16; off<<=1)
      #pragma unroll
      for (int r=0; r<4; ++r){ ps[r]+=__shfl_xor(ps[r],off); pd[r]+=__shfl_xor(pd[r],off); }
    if (of==0){
      #pragma unroll
      for (int r=0; r<4; ++r){
        int i = w*16 + kg*4 + r;
        src_l[ct*128+i]=ps[r]; dst_l[ct*128+i]=pd[r];
      }
    }
    uint32_t p0 = packbf(acc[ct][0], acc[ct][1]);
    uint32_t p1 = packbf(acc[ct][2], acc[ct][3]);
    uint32_t* dsth = hf_u + ((ct*4+ks_h)*64 + kgp*16 + of)*4 + vv;
    *(uint2*)dsth = make_uint2(p0, p1);
  }
  __syncthreads();

  // ---------- Phase 2: out1 = softmax(lrelu(src+dst)) @ h, fused elu + W2 dot ----------
  const int hd = w;                               // one head per wave
  float b1v  = b1[of];
  float w2c0 = w2[s*256 + (hd*16+of)*2 + 0];
  float w2c1 = w2[s*256 + (hd*16+of)*2 + 1];
  short8 hb[4];                                   // h B-frags: single b128 each
  #pragma unroll
  for (int ks=0; ks<4; ++ks)
    hb[ks] = *(const short8*)(hf + ((hd*4+ks)*64 + lane)*16);

  for (int rt=0; rt<8; ++rt){
    const int im = rt*16 + of;                    // A-layout row
    float srcv = src_l[hd*128 + im];
    uint4 mrow = mask4[im];
    floatx4 acc2 = (floatx4){0.f,0.f,0.f,0.f};
    float zp = 0.f;
    #pragma unroll
    for (int ks=0; ks<4; ++ks){
      const float* dp = dst_l + hd*128 + ks*32 + kg*8;
      float4 d0 = *(const float4*)dp, d1 = *(const float4*)(dp+4);
      uint32_t mw = (ks==0)?mrow.x:(ks==1)?mrow.y:(ks==2)?mrow.z:mrow.w;
      uint32_t mbyte = mw >> (kg*8);
      float dj[8] = {d0.x,d0.y,d0.z,d0.w,d1.x,d1.y,d1.z,d1.w};
      float e[8];
      #pragma unroll
      for (int jj=0; jj<8; ++jj){
        float t0 = srcv + dj[jj];
        float lr = fmaxf(t0, 0.2f*t0);
        float ev = __expf(lr);                    // logits bounded; no max-sub needed
        ev = ((mbyte>>jj)&1u) ? ev : 0.f;
        e[jj]=ev; zp += ev;
      }
      F8 fr;
      fr.u[0]=packbf(e[0],e[1]); fr.u[1]=packbf(e[2],e[3]);
      fr.u[2]=packbf(e[4],e[5]); fr.u[3]=packbf(e[6],e[7]);
      acc2 = __builtin_amdgcn_mfma_f32_16x16x32_bf16(fr.s8, hb[ks], acc2, 0,0,0);
    }
    float zr = zp + __shfl_xor(zp,16); zr += __shfl_xor(zr,32);
    float zi = __builtin_amdgcn_rcpf(zr);
    float pc0[4], pc1[4];
    #pragma unroll
    for (int r=0; r<4; ++r){
      float ziR = __shfl(zi, kg*4+r);
      float o  = fmaf(acc2[r], ziR, b1v);
      float oe = (o>0.f) ? o : (__expf(o)-1.f);   // elu
      pc0[r]=oe*w2c0; pc1[r]=oe*w2c1;
    }
    #pragma unroll
    for (int off=1; off<16; off<<=1)
      #pragma unroll
      for (int r=0; r<4; ++r){ pc0[r]+=__shfl_xor(pc0[r],off); pc1[r]+=__shfl_xor(pc1[r],off); }
    if (of==0){
      #pragma unroll
      for (int r=0; r<4; ++r){
        int i = rt*16 + kg*4 + r;
        h2p[w*128 + i] = make_float2(pc0[r], pc1[r]);
      }
    }
  }
  __syncthreads();

  // ---------- Layer 2 (ego row only) + log_softmax + atomic mean ----------
  {
    const int jn = t>>1, cc = t&1;
    const bool act = (t<256);
    float hv=0.f, v=-1e9f;
    if (act){
      #pragma unroll
      for (int ww=0; ww<8; ++ww){
        float2 p = h2p[ww*128+jn];
        hv += cc ? p.y : p.x;
      }
      float th2 = fast_tanh(hv);
      float ps2 = th2*a_src2[s*2+cc];
      float pd2 = th2*a_dst2[s*2+cc];
      ps2 += __shfl_xor(ps2,1);
      pd2 += __shfl_xor(pd2,1);
      if (cc==0) d2_l[jn]=pd2;
      if (t==254) red[40]=ps2;                    // ego node (jn=127)
    }
    __syncthreads();
    if (act){
      float t0 = red[40] + d2_l[jn];
      float lg = fmaxf(t0, 0.2f*t0);
      uint32_t bit = (mask_l[127*4 + (jn>>5)] >> (jn&31)) & 1u;
      v = bit ? lg : -1e9f;
    }
    float mloc = v;
    #pragma unroll
    for (int off=32; off>=1; off>>=1) mloc = fmaxf(mloc, __shfl_xor(mloc,off));
    if (lane==0) red[w]=mloc;
    __syncthreads();
    float M = fmaxf(fmaxf(red[0],red[1]), fmaxf(red[2],red[3]));
    float e2 = act ? __expf(v-M) : 0.f;
    float vA = e2*hv;
    float vZ = (cc==0 && act) ? e2 : 0.f;
    #pragma unroll
    for (int off=2; off<=32; off<<=1){ vA+=__shfl_xor(vA,off); vZ+=__shfl_xor(vZ,off); }
    if (lane==0){ red[8+w]=vA; red[24+w]=vZ; }
    if (lane==1){ red[16+w]=vA; }
    __syncthreads();
    if (t==0){
      float S0 = red[8]+red[9]+red[10]+red[11];
      float S1 = red[16]+red[17]+red[18]+red[19];
      float Z  = red[24]+red[25]+red[26]+red[27];
      float o0 = S0/Z + b2[0];
      float o1 = S1/Z + b2[1];
      float mm = fmaxf(o0,o1);
      float lse = mm + logf(__expf(o0-mm)+__expf(o1-mm));
      atomicAdd(outp + bb*2 + 0, 0.25f*(o0 - lse));
      atomicAdd(outp + bb*2 + 1, 0.25f*(o1 - lse));
    }
  }
}

extern "C" void kernel_launch(void* const* d_in, const int* in_sizes, int n_in,
                              void* d_out, int out_size, void* d_ws, size_t ws_size,
                              hipStream_t stream) {
  const float* x      = (const float*)d_in[0];
  const float* emb    = (const float*)d_in[1];
  const int*   adj    = (const int*)d_in[2];
  const float* w1     = (const float*)d_in[3];
  const float* a_src1 = (const float*)d_in[4];
  const float* a_dst1 = (const float*)d_in[5];
  const float* b1     = (const float*)d_in[6];
  const float* w2     = (const float*)d_in[7];
  const float* a_src2 = (const float*)d_in[8];
  const float* a_dst2 = (const float*)d_in[9];
  const float* b2     = (const float*)d_in[10];

  uint32_t* mask_ws = (uint32_t*)d_ws;
  uint32_t* w1f     = (uint32_t*)((char*)d_ws + WS_MASK_BYTES);

  hipMemsetAsync(d_out, 0, (size_t)out_size*sizeof(float), stream);
  prep<<<dim3(1056), dim3(256), 0, stream>>>(adj, w1, mask_ws, w1f);
  gat_fused<<<dim3(512), dim3(512), 0, stream>>>(x, emb, a_src1, a_dst1, b1,
                                                 w2, a_src2, a_dst2, b2,
                                                 mask_ws, (const char*)w1f,
                                                 (float*)d_out);
}

// Round 4
// 138.976 us; speedup vs baseline: 1.7634x; 1.0061x over previous
//
#include <hip/hip_runtime.h>
#include <stdint.h>
#include <math.h>

typedef __attribute__((ext_vector_type(8))) short short8;
typedef __attribute__((ext_vector_type(4))) float floatx4;

// ---------------- LDS layout (26624 B -> 4 blocks/CU at 8 waves) ----------------
#define L_HF    0        // 16384: W1 B-frags, then h B-frags: [ct(4)][ks(4)][lane(64)] x 16B
#define L_SRC   16384    // 2048 : att_src [4][128] f32 (pre-scaled by log2e)
#define L_DST   18432    // 2048 : att_dst [4][128] f32 (pre-scaled by log2e)
#define L_MASK  20480    // 2048 : mask bits [128 rows][16 B]
#define L_H2P   22528    // 4096 : layer-2 partials float2[4 heads][128 nodes]
#define L_SIZE  26624

union F8 { short8 s8; uint32_t u[4]; };

#if __has_builtin(__builtin_amdgcn_exp2f)
#define EXP2F __builtin_amdgcn_exp2f
#else
#define EXP2F exp2f
#endif
#define LOG2E 1.4426950408889634f

__device__ __forceinline__ uint32_t packbf(float a, float b){
  uint32_t ua = __float_as_uint(a), ub = __float_as_uint(b);
  uint32_t ra = (ua + 0x7fffu + ((ua>>16)&1u)) >> 16;   // RNE bf16
  uint32_t rb = (ub + 0x7fffu + ((ub>>16)&1u)) >> 16;
  return ra | (rb<<16);
}
// truncation pack (1 inst): low16 = hi16(a), high16 = hi16(b)
__device__ __forceinline__ uint32_t packbf_t(float a, float b){
  return __builtin_amdgcn_perm(__float_as_uint(b), __float_as_uint(a), 0x07060302u);
}
__device__ __forceinline__ float fast_tanh(float x){
  float e = __expf(2.f*x);
  return 1.f - 2.f*__builtin_amdgcn_rcpf(e + 1.f);
}

// ---- fused GAT: one block per (s, b, head-half), 8 waves ----
__global__ __launch_bounds__(512,8) void gat_fused(
    const float* __restrict__ x,  const float* __restrict__ emb,
    const int* __restrict__ adj,  const float* __restrict__ w1,
    const float* __restrict__ a_src1, const float* __restrict__ a_dst1,
    const float* __restrict__ b1, const float* __restrict__ w2,
    float* __restrict__ ws_h2)
{
  __shared__ __align__(16) char smem[L_SIZE];
  char*     hf    = smem + L_HF;
  uint32_t* hf_u  = (uint32_t*)(smem + L_HF);
  float*    src_l = (float*)(smem + L_SRC);
  float*    dst_l = (float*)(smem + L_DST);
  uint32_t* mask_l= (uint32_t*)(smem + L_MASK);
  const uint4* mask4 = (const uint4*)(smem + L_MASK);
  float2*   h2p   = (float2*)(smem + L_H2P);

  const int t    = threadIdx.x;
  const int blk  = blockIdx.x;
  const int s    = blk >> 8;
  const int bb   = (blk & 255) >> 1;
  const int half = blk & 1;
  const int lane = t & 63, w = t >> 6;
  const int of = lane & 15, kg = lane >> 4;

  // ---------- Phase 0a: A-frags direct from global (rows w*16+of) ----------
  const int arow = w*16 + of;
  const float* xrow = x   + ((size_t)bb*128 + arow)*64;
  const float* erow = emb + ((size_t)bb*128 + arow)*64;
  short8 af[4];
  #pragma unroll
  for (int ks=0; ks<4; ++ks){
    int k = ks*32 + kg*8;
    const float* p = (k<64) ? (xrow+k) : (erow + (k-64));
    float4 f0 = *(const float4*)p, f1 = *(const float4*)(p+4);
    F8 fr;
    fr.u[0]=packbf(f0.x,f0.y); fr.u[1]=packbf(f0.z,f0.w);
    fr.u[2]=packbf(f1.x,f1.y); fr.u[3]=packbf(f1.z,f1.w);
    af[ks]=fr.s8;
  }

  // ---------- Phase 0b: stage this block's 4 heads of W1 as bf16 B-frags ----------
  {
    const float* w1s = w1 + (size_t)s*16384 + half*8192;  // 4 heads x 128 x 16
    #pragma unroll
    for (int r=0; r<2; ++r){
      int q = t + r*512;                     // 0..1023 = (ct*4+ks)*64 + qlane
      int ql = q & 63, ks = (q>>6)&3, ct = q>>8;
      const float* wp = w1s + ct*2048 + (ks*32 + (ql>>4)*8)*16 + (ql&15);
      F8 fr;
      fr.u[0]=packbf(wp[0],  wp[16]);
      fr.u[1]=packbf(wp[32], wp[48]);
      fr.u[2]=packbf(wp[64], wp[80]);
      fr.u[3]=packbf(wp[96], wp[112]);
      *(short8*)(hf + ((ct*4+ks)*64 + ql)*16) = fr.s8;
    }
  }

  // ---------- Phase 0c: adjacency ballot -> mask bits (wave w: rows w*16..+15) ----------
  {
    const int* adjb = adj + (size_t)bb*16384;
    #pragma unroll 4
    for (int rr=0; rr<16; ++rr){
      const int row = w*16 + rr;
      const int* ar = adjb + row*128;
      uint64_t m0 = __ballot(ar[lane] != 0);
      uint64_t m1 = __ballot(ar[64+lane] != 0);
      if (lane == 0)
        ((uint4*)mask_l)[row] = make_uint4((uint32_t)m0,(uint32_t)(m0>>32),
                                           (uint32_t)m1,(uint32_t)(m1>>32));
    }
  }
  __syncthreads();

  // ---------- Phase 1: h = x0 @ W1 via MFMA ----------
  floatx4 acc[4];
  #pragma unroll
  for (int ct=0; ct<4; ++ct) acc[ct]=(floatx4){0.f,0.f,0.f,0.f};
  #pragma unroll
  for (int ct=0; ct<4; ++ct)
    #pragma unroll
    for (int ks=0; ks<4; ++ks){
      short8 bfr = *(const short8*)(hf + ((ct*4+ks)*64 + lane)*16);
      acc[ct] = __builtin_amdgcn_mfma_f32_16x16x32_bf16(af[ks], bfr, acc[ct], 0,0,0);
    }
  __syncthreads();                            // all W1-frag reads done before h overwrite

  // epilogue: tanh -> att partials (x log2e); h -> LDS in B-frag order
  const int ks_h = w>>1, kgp = (w&1)*2 + (kg>>1), vv = (kg&1)*2;
  #pragma unroll
  for (int ct=0; ct<4; ++ct){
    const int ghd = half*4 + ct;
    float asv = a_src1[s*128 + ghd*16 + of] * LOG2E;
    float adv = a_dst1[s*128 + ghd*16 + of] * LOG2E;
    float ps[4], pd[4];
    #pragma unroll
    for (int r=0; r<4; ++r){
      float th = fast_tanh(acc[ct][r]);
      ps[r] = th*asv; pd[r] = th*adv;
    }
    #pragma unroll
    for (int off=1; off<16; off<<=1)
      #pragma unroll
      for (int r=0; r<4; ++r){ ps[r]+=__shfl_xor(ps[r],off); pd[r]+=__shfl_xor(pd[r],off); }
    if (of==0){
      #pragma unroll
      for (int r=0; r<4; ++r){
        int i = w*16 + kg*4 + r;
        src_l[ct*128+i]=ps[r]; dst_l[ct*128+i]=pd[r];
      }
    }
    uint32_t p0 = packbf(acc[ct][0], acc[ct][1]);
    uint32_t p1 = packbf(acc[ct][2], acc[ct][3]);
    uint32_t* dsth = hf_u + ((ct*4+ks_h)*64 + kgp*16 + of)*4 + vv;
    *(uint2*)dsth = make_uint2(p0, p1);
  }
  __syncthreads();

  // ---------- Phase 2: softmax(lrelu(src+dst)) @ h, fused elu + W2 dot ----------
  const int lhd = w >> 1;                     // 2 waves per head
  const int ghd = half*4 + lhd;
  float b1v  = b1[of];
  float w2c0 = w2[s*256 + (ghd*16+of)*2 + 0];
  float w2c1 = w2[s*256 + (ghd*16+of)*2 + 1];
  short8 hb[4];
  #pragma unroll
  for (int ks=0; ks<4; ++ks)
    hb[ks] = *(const short8*)(hf + ((lhd*4+ks)*64 + lane)*16);

  #pragma unroll
  for (int rtl=0; rtl<4; ++rtl){
    const int rt = (w&1)*4 + rtl;
    const int im = rt*16 + of;                // A-layout row
    float srcv = src_l[lhd*128 + im];
    uint4 mrow = mask4[im];
    floatx4 acc2 = (floatx4){0.f,0.f,0.f,0.f};
    float zp = 0.f;
    #pragma unroll
    for (int ks=0; ks<4; ++ks){
      const float* dp = dst_l + lhd*128 + ks*32 + kg*8;
      float4 d0 = *(const float4*)dp, d1 = *(const float4*)(dp+4);
      uint32_t mw = (ks==0)?mrow.x:(ks==1)?mrow.y:(ks==2)?mrow.z:mrow.w;
      uint32_t mbyte = mw >> (kg*8);
      float dj[8] = {d0.x,d0.y,d0.z,d0.w,d1.x,d1.y,d1.z,d1.w};
      float e[8];
      #pragma unroll
      for (int jj=0; jj<8; ++jj){
        float t0 = srcv + dj[jj];             // already x log2e
        float lr = fmaxf(t0, 0.2f*t0);
        float ev = EXP2F(lr);
        ev = ((mbyte>>jj)&1u) ? ev : 0.f;
        e[jj]=ev; zp += ev;
      }
      F8 fr;
      fr.u[0]=packbf_t(e[0],e[1]); fr.u[1]=packbf_t(e[2],e[3]);
      fr.u[2]=packbf_t(e[4],e[5]); fr.u[3]=packbf_t(e[6],e[7]);
      acc2 = __builtin_amdgcn_mfma_f32_16x16x32_bf16(fr.s8, hb[ks], acc2, 0,0,0);
    }
    float zr = zp + __shfl_xor(zp,16); zr += __shfl_xor(zr,32);
    float zi = __builtin_amdgcn_rcpf(zr);
    float pc0[4], pc1[4];
    #pragma unroll
    for (int r=0; r<4; ++r){
      float ziR = __shfl(zi, kg*4+r);
      float o  = fmaf(acc2[r], ziR, b1v);
      float oe = (o>0.f) ? o : (__expf(o)-1.f);   // elu
      pc0[r]=oe*w2c0; pc1[r]=oe*w2c1;
    }
    #pragma unroll
    for (int off=1; off<16; off<<=1)
      #pragma unroll
      for (int r=0; r<4; ++r){ pc0[r]+=__shfl_xor(pc0[r],off); pc1[r]+=__shfl_xor(pc1[r],off); }
    if (of==0){
      #pragma unroll
      for (int r=0; r<4; ++r){
        int i = rt*16 + kg*4 + r;
        h2p[lhd*128 + i] = make_float2(pc0[r], pc1[r]);
      }
    }
  }
  __syncthreads();

  // ---------- block-partial h2 (sum over this block's 4 heads) -> ws ----------
  if (t < 256){
    const int jn = t>>1, cc = t&1;
    float hv = 0.f;
    #pragma unroll
    for (int hd2=0; hd2<4; ++hd2){
      float2 p = h2p[hd2*128+jn];
      hv += cc ? p.y : p.x;
    }
    ws_h2[(size_t)blk*256 + t] = hv;
  }
}

// ---- tail: layer-2 ego-row softmax + log_softmax + mean over S ----
__global__ __launch_bounds__(256) void gat_tail(
    const float* __restrict__ ws_h2, const int* __restrict__ adj,
    const float* __restrict__ a_src2, const float* __restrict__ a_dst2,
    const float* __restrict__ b2, float* __restrict__ out)
{
  __shared__ float d2_l[128];
  __shared__ float red[16];
  __shared__ float srcE;
  const int bb = blockIdx.x, t = threadIdx.x;
  const int jn = t>>1, cc = t&1, lane = t&63, w = t>>6;
  const uint32_t bit = (adj[((size_t)bb*128+127)*128 + jn] != 0) ? 1u : 0u;
  float acc0=0.f, acc1=0.f;
  for (int s=0; s<4; ++s){
    float hv = ws_h2[(size_t)(s*256 + bb*2 + 0)*256 + t]
             + ws_h2[(size_t)(s*256 + bb*2 + 1)*256 + t];
    float th2 = fast_tanh(hv);
    float ps2 = th2*a_src2[s*2+cc];
    float pd2 = th2*a_dst2[s*2+cc];
    ps2 += __shfl_xor(ps2,1);
    pd2 += __shfl_xor(pd2,1);
    if (s) __syncthreads();                  // WAR on d2_l/srcE/red
    if (cc==0) d2_l[jn]=pd2;
    if (t==254) srcE=ps2;                    // ego node jn=127
    __syncthreads();
    float t0 = srcE + d2_l[jn];
    float lg = fmaxf(t0, 0.2f*t0);
    float v  = bit ? lg : -1e9f;
    float mloc = v;
    #pragma unroll
    for (int off=32; off>=1; off>>=1) mloc = fmaxf(mloc, __shfl_xor(mloc,off));
    if (lane==0) red[w]=mloc;
    __syncthreads();
    float M = fmaxf(fmaxf(red[0],red[1]), fmaxf(red[2],red[3]));
    float e2 = __expf(v-M);
    float vA = e2*hv;
    float vZ = (cc==0) ? e2 : 0.f;
    #pragma unroll
    for (int off=2; off<=32; off<<=1){ vA+=__shfl_xor(vA,off); vZ+=__shfl_xor(vZ,off); }
    if (lane==0){ red[4+w]=vA; red[12+w]=vZ; }
    if (lane==1){ red[8+w]=vA; }
    __syncthreads();
    if (t==0){
      float S0 = red[4]+red[5]+red[6]+red[7];
      float S1 = red[8]+red[9]+red[10]+red[11];
      float Z  = red[12]+red[13]+red[14]+red[15];
      float o0 = S0/Z + b2[0];
      float o1 = S1/Z + b2[1];
      float mm = fmaxf(o0,o1);
      float lse = mm + logf(__expf(o0-mm)+__expf(o1-mm));
      acc0 += 0.25f*(o0 - lse);
      acc1 += 0.25f*(o1 - lse);
    }
  }
  if (t==0){ out[bb*2+0]=acc0; out[bb*2+1]=acc1; }
}

extern "C" void kernel_launch(void* const* d_in, const int* in_sizes, int n_in,
                              void* d_out, int out_size, void* d_ws, size_t ws_size,
                              hipStream_t stream) {
  const float* x      = (const float*)d_in[0];
  const float* emb    = (const float*)d_in[1];
  const int*   adj    = (const int*)d_in[2];
  const float* w1     = (const float*)d_in[3];
  const float* a_src1 = (const float*)d_in[4];
  const float* a_dst1 = (const float*)d_in[5];
  const float* b1     = (const float*)d_in[6];
  const float* w2     = (const float*)d_in[7];
  const float* a_src2 = (const float*)d_in[8];
  const float* a_dst2 = (const float*)d_in[9];
  const float* b2     = (const float*)d_in[10];

  float* ws_h2 = (float*)d_ws;   // 1024 blocks x 256 floats = 1 MB

  gat_fused<<<dim3(1024), dim3(512), 0, stream>>>(x, emb, adj, w1, a_src1, a_dst1,
                                                  b1, w2, ws_h2);
  gat_tail<<<dim3(128), dim3(256), 0, stream>>>(ws_h2, adj, a_src2, a_dst2, b2,
                                                (float*)d_out);
}